// Round 3
// baseline (1585.429 us; speedup 1.0000x reference)
//
#include <hip/hip_runtime.h>
#include <cstdint>
#include <cstddef>

// ---------------------------------------------------------------------------
// DockPointNet fused edge-MLP + segment-max, f16 MFMA version.
//   msg[e](47) = [x[src] | ppf | edge_attr]
//   h1 = LN(relu(msg @ W1 + b1))   via mfma_f32_16x16x32_f16, 3 N-frags
//   h2 = LN(relu(h1  @ W2 + b2))   via mfma_f32_16x16x32_f16, 8 N-frags
//   out[n] = segment-max over dst, empty -> 0
// 64-edge tile / block, 16 edges / wave, barrier-free tile loop.
// Round 3: (1) test-before-atomic (atomicMax only on record-breakers --
// round 2 showed 273 G atomics/s == TCC atomic rate limit); (2) h1 aliased
// into msgA (LDS 44->34.8 KB, 3->4 blocks/CU).
// ---------------------------------------------------------------------------

typedef _Float16 f16x8 __attribute__((ext_vector_type(8)));
typedef float    f32x4 __attribute__((ext_vector_type(4)));

#define ENC_NEGINF 0x007FFFFFu   // fenc(-inf)
#define LDK 72                   // padded K stride (bank-stride keeps b128 cheap)

__device__ __forceinline__ unsigned fenc(float f) {
    unsigned u = __float_as_uint(f);
    return (u & 0x80000000u) ? ~u : (u | 0x80000000u);
}

__global__ void init_out_kernel(unsigned* __restrict__ out, int n4) {
    int i = blockIdx.x * blockDim.x + threadIdx.x;
    if (i < n4) {
        ((uint4*)out)[i] = make_uint4(ENC_NEGINF, ENC_NEGINF, ENC_NEGINF, ENC_NEGINF);
    }
}

__global__ void finalize_out_kernel(float* __restrict__ out, int n) {
    int i = blockIdx.x * blockDim.x + threadIdx.x;
    if (i < n) {
        unsigned k = __float_as_uint(out[i]);
        float r;
        if (k == ENC_NEGINF) {
            r = 0.0f;                       // empty segment -> 0 (isfinite guard)
        } else {
            unsigned u = (k & 0x80000000u) ? (k ^ 0x80000000u) : ~k;
            r = __uint_as_float(u);
        }
        out[i] = r;
    }
}

__global__ __launch_bounds__(256) void edge_kernel(
    const float* __restrict__ x,   const float* __restrict__ pos,
    const float* __restrict__ nrm, const float* __restrict__ ea,
    const float* __restrict__ W1,  const float* __restrict__ b1,
    const float* __restrict__ g1,  const float* __restrict__ be1,
    const float* __restrict__ W2,  const float* __restrict__ b2,
    const float* __restrict__ g2,  const float* __restrict__ be2,
    const int* __restrict__ srcI,  const int* __restrict__ dstI,
    unsigned* __restrict__ out, int E, int ntiles)
{
    __shared__ _Float16 W1t[48][LDK];    // [n][k]  (B^T layout: frag = ds_read_b128)
    __shared__ _Float16 W2t[128][LDK];   // [n][k]
    __shared__ _Float16 msgA[64][LDK];   // [edge][k]; h1 aliased here after GEMM1
    __shared__ int dst_s[64];

    const int lane = threadIdx.x & 63;
    const int w    = threadIdx.x >> 6;   // 4 waves / block
    const int c16  = lane & 15;          // fragment col / A-row
    const int g    = lane >> 4;          // k-group (A/B) and row-group (C)

    // ---- stage weights to LDS, transposed + f16 + zero-padded ----
    for (int i = threadIdx.x; i < 48 * 64; i += 256) {
        int n = i >> 6, k = i & 63;
        W1t[n][k] = (n < 47 && k < 47) ? (_Float16)W1[k * 47 + n] : (_Float16)0.f;
    }
    for (int i = threadIdx.x; i < 128 * 64; i += 256) {
        int n = i >> 6, k = i & 63;
        W2t[n][k] = (k < 47) ? (_Float16)W2[k * 128 + n] : (_Float16)0.f;
    }
    // zero msg (pad cols must stay zero; valid cols rewritten per tile)
    for (int i = threadIdx.x; i < 64 * LDK; i += 256) {
        (&msgA[0][0])[i] = (_Float16)0.f;
    }

    // ---- per-lane LN params ----
    float b1v[3], g1v[3], be1v[3];
#pragma unroll
    for (int n = 0; n < 3; ++n) {
        int cc = n * 16 + c16;
        bool vld = cc < 47;
        b1v[n]  = vld ? b1[cc]  : 0.f;
        g1v[n]  = vld ? g1[cc]  : 0.f;
        be1v[n] = vld ? be1[cc] : 0.f;
    }
    float b2v[8], g2v[8], be2v[8];
#pragma unroll
    for (int n = 0; n < 8; ++n) {
        int cc = n * 16 + c16;
        b2v[n] = b2[cc]; g2v[n] = g2[cc]; be2v[n] = be2[cc];
    }
    __syncthreads();

    for (int tile = blockIdx.x; tile < ntiles; tile += gridDim.x) {
        const int base = tile * 64 + w * 16;   // this wave's 16 edges
        const int row0 = w * 16;

        // ---------------- Phase 1: build msg rows (wave-private) ----------------
        // x_j: 2 edges / iter, half-wave each (coalesced 128B)
#pragma unroll
        for (int i = 0; i < 8; ++i) {
            int el = i * 2 + (lane >> 5);
            int e  = base + el;
            int c  = lane & 31;
            float v = 0.f;
            if (e < E) v = x[(size_t)srcI[e] * 32 + c];
            msgA[row0 + el][c] = (_Float16)v;
        }
        // edge_attr: lanes 0..43 cover 4 edges x 11 ch per iter
        if (lane < 44) {
            int eg = lane / 11, c = lane - eg * 11;
#pragma unroll
            for (int i = 0; i < 4; ++i) {
                int el = i * 4 + eg;
                int e  = base + el;
                float v = 0.f;
                if (e < E) v = ea[(size_t)e * 11 + c];
                msgA[row0 + el][36 + c] = (_Float16)v;
            }
        }
        // geometry: lane = g*16 + el, g = which angle (0..2), el = edge 0..15
        if (lane < 48) {
            int el = c16;
            int e  = base + el;
            int s = 0, d = 0;
            bool vld = e < E;
            if (vld) { s = srcI[e]; d = dstI[e]; }
            float pix = pos[d * 3 + 0], piy = pos[d * 3 + 1], piz = pos[d * 3 + 2];
            float pjx = pos[s * 3 + 0], pjy = pos[s * 3 + 1], pjz = pos[s * 3 + 2];
            float nix = nrm[d * 3 + 0], niy = nrm[d * 3 + 1], niz = nrm[d * 3 + 2];
            float njx = nrm[s * 3 + 0], njy = nrm[s * 3 + 1], njz = nrm[s * 3 + 2];
            float px = pjx - pix, py = pjy - piy, pz = pjz - piz;
            float v1x, v1y, v1z, v2x, v2y, v2z;
            if (g == 0)      { v1x = nix; v1y = niy; v1z = niz; v2x = px;  v2y = py;  v2z = pz;  }
            else if (g == 1) { v1x = njx; v1y = njy; v1z = njz; v2x = px;  v2y = py;  v2z = pz;  }
            else             { v1x = nix; v1y = niy; v1z = niz; v2x = njx; v2y = njy; v2z = njz; }
            float cx = v1y * v2z - v1z * v2y;
            float cy = v1z * v2x - v1x * v2z;
            float cz = v1x * v2y - v1y * v2x;
            float ang = atan2f(sqrtf(cx * cx + cy * cy + cz * cz),
                               v1x * v2x + v1y * v2y + v1z * v2z);
            msgA[row0 + el][33 + g] = (_Float16)ang;
            if (g == 0) {
                msgA[row0 + el][32] = (_Float16)sqrtf(px * px + py * py + pz * pz);
                dst_s[row0 + el] = vld ? d : -1;
            }
        }
        // no barrier needed: all LDS rows above are wave-private

        // ---------------- Phase 2: GEMM1 (16x48 = 6 MFMA) + LN1 ----------------
        f32x4 acc1[3];
#pragma unroll
        for (int n = 0; n < 3; ++n) acc1[n] = (f32x4){0.f, 0.f, 0.f, 0.f};
#pragma unroll
        for (int ks = 0; ks < 2; ++ks) {
            f16x8 a = *(const f16x8*)&msgA[row0 + c16][ks * 32 + g * 8];
#pragma unroll
            for (int n = 0; n < 3; ++n) {
                f16x8 b = *(const f16x8*)&W1t[n * 16 + c16][ks * 32 + g * 8];
                acc1[n] = __builtin_amdgcn_mfma_f32_16x16x32_f16(a, b, acc1[n], 0, 0, 0);
            }
        }
        // LN1 -> write h1 back into msgA (GEMM1 reads all done; rows wave-private)
#pragma unroll
        for (int q = 0; q < 4; ++q) {
            float t0 = fmaxf(acc1[0][q] + b1v[0], 0.f);
            float t1 = fmaxf(acc1[1][q] + b1v[1], 0.f);
            float t2 = fmaxf(acc1[2][q] + b1v[2], 0.f);   // col 47 -> 0
            float s = t0 + t1 + t2;
            float s2 = t0 * t0 + t1 * t1 + t2 * t2;
#pragma unroll
            for (int m = 1; m < 16; m <<= 1) {
                s  += __shfl_xor(s,  m, 64);
                s2 += __shfl_xor(s2, m, 64);
            }
            float mu  = s * (1.f / 47.f);
            float var = s2 * (1.f / 47.f) - mu * mu;
            float rs  = rsqrtf(var + 1e-5f);
            int r = row0 + 4 * g + q;
            msgA[r][c16]      = (_Float16)((t0 - mu) * rs * g1v[0] + be1v[0]);
            msgA[r][16 + c16] = (_Float16)((t1 - mu) * rs * g1v[1] + be1v[1]);
            msgA[r][32 + c16] = (_Float16)((t2 - mu) * rs * g1v[2] + be1v[2]);  // col47 -> 0
        }

        // ---------------- Phase 3: GEMM2 (16x128 = 16 MFMA) + LN2 + scatter ----
        f32x4 acc2[8];
#pragma unroll
        for (int n = 0; n < 8; ++n) acc2[n] = (f32x4){0.f, 0.f, 0.f, 0.f};
#pragma unroll
        for (int ks = 0; ks < 2; ++ks) {
            f16x8 a = *(const f16x8*)&msgA[row0 + c16][ks * 32 + g * 8];
#pragma unroll
            for (int n = 0; n < 8; ++n) {
                f16x8 b = *(const f16x8*)&W2t[n * 16 + c16][ks * 32 + g * 8];
                acc2[n] = __builtin_amdgcn_mfma_f32_16x16x32_f16(a, b, acc2[n], 0, 0, 0);
            }
        }
        int4 dd = *(const int4*)&dst_s[row0 + 4 * g];
#pragma unroll
        for (int q = 0; q < 4; ++q) {
            float t[8];
            float s = 0.f, s2 = 0.f;
#pragma unroll
            for (int n = 0; n < 8; ++n) {
                t[n] = fmaxf(acc2[n][q] + b2v[n], 0.f);
                s += t[n]; s2 += t[n] * t[n];
            }
#pragma unroll
            for (int m = 1; m < 16; m <<= 1) {
                s  += __shfl_xor(s,  m, 64);
                s2 += __shfl_xor(s2, m, 64);
            }
            float mu  = s * (1.f / 128.f);
            float var = s2 * (1.f / 128.f) - mu * mu;
            float rs  = rsqrtf(var + 1e-5f);
            int d = (&dd.x)[q];
            if (d >= 0) {
                unsigned* orow = out + (size_t)d * 128u;
                // test-before-atomic: only record-breaking values pay the
                // memory-side atomic (273 G atomics/s TCC rate limit, round 2).
                // Stale/racy reads are conservative: values only increase.
                unsigned enc[8], cur[8];
#pragma unroll
                for (int n = 0; n < 8; ++n) {
                    float o = (t[n] - mu) * rs * g2v[n] + be2v[n];
                    enc[n] = fenc(o);
                    cur[n] = orow[n * 16 + c16];
                }
#pragma unroll
                for (int n = 0; n < 8; ++n) {
                    if (enc[n] > cur[n]) atomicMax(orow + n * 16 + c16, enc[n]);
                }
            }
        }
    }
}

extern "C" void kernel_launch(void* const* d_in, const int* in_sizes, int n_in,
                              void* d_out, int out_size, void* d_ws, size_t ws_size,
                              hipStream_t stream) {
    const float* x   = (const float*)d_in[0];
    const float* pos = (const float*)d_in[1];
    const float* nrm = (const float*)d_in[2];
    const float* ea  = (const float*)d_in[3];
    const float* W1  = (const float*)d_in[4];
    const float* b1  = (const float*)d_in[5];
    const float* g1  = (const float*)d_in[6];
    const float* be1 = (const float*)d_in[7];
    const float* W2  = (const float*)d_in[8];
    const float* b2  = (const float*)d_in[9];
    const float* g2  = (const float*)d_in[10];
    const float* be2 = (const float*)d_in[11];
    const int*   idx = (const int*)d_in[12];

    const int N = in_sizes[0] / 32;
    const int E = in_sizes[3] / 11;
    const int* srcI = idx;
    const int* dstI = idx + E;

    unsigned* outU = (unsigned*)d_out;
    const int n = N * 128;

    init_out_kernel<<<(n / 4 + 255) / 256, 256, 0, stream>>>(outU, n / 4);

    const int ntiles = (E + 63) / 64;
    const int grid = ntiles < 4096 ? ntiles : 4096;
    edge_kernel<<<grid, 256, 0, stream>>>(x, pos, nrm, ea,
                                          W1, b1, g1, be1,
                                          W2, b2, g2, be2,
                                          srcI, dstI, outU, E, ntiles);

    finalize_out_kernel<<<(n + 255) / 256, 256, 0, stream>>>((float*)d_out, n);
}

// Round 4
// 1435.846 us; speedup vs baseline: 1.1042x; 1.1042x over previous
//
#include <hip/hip_runtime.h>
#include <cstdint>
#include <cstddef>

// ---------------------------------------------------------------------------
// DockPointNet fused edge-MLP + segment-max, f16 MFMA + CSR counting sort.
// Round 4: round-2 profile showed 409.6M scattered atomics at 273 G/s = the
// TCC atomic rate limit (1.5 ms). Fix: counting-sort edges by dst on device,
// then segment-max in LDS per 16-edge window -> ~10x fewer atomics, interior
// segments use plain coalesced stores. Max is order-independent in FP, so the
// racy scatter order stays bit-deterministic.
// ---------------------------------------------------------------------------

typedef _Float16 f16x8 __attribute__((ext_vector_type(8)));
typedef _Float16 f16x2 __attribute__((ext_vector_type(2)));
typedef float    f32x4 __attribute__((ext_vector_type(4)));

#define ENC_NEGINF 0x007FFFFFu   // fenc(-inf)
#define LDK 72                   // msg/W row stride (f16)
#define LDH 132                  // h2 row stride (f16): 264B row, 4-row stride = 8 banks

__device__ __forceinline__ unsigned fenc(float f) {
    unsigned u = __float_as_uint(f);
    return (u & 0x80000000u) ? ~u : (u | 0x80000000u);
}

__global__ void init_out_kernel(unsigned* __restrict__ out, int n4) {
    int i = blockIdx.x * blockDim.x + threadIdx.x;
    if (i < n4)
        ((uint4*)out)[i] = make_uint4(ENC_NEGINF, ENC_NEGINF, ENC_NEGINF, ENC_NEGINF);
}

__global__ void finalize_out_kernel(float* __restrict__ out, int n) {
    int i = blockIdx.x * blockDim.x + threadIdx.x;
    if (i < n) {
        unsigned k = __float_as_uint(out[i]);
        float r;
        if (k == ENC_NEGINF) r = 0.0f;
        else {
            unsigned u = (k & 0x80000000u) ? (k ^ 0x80000000u) : ~k;
            r = __uint_as_float(u);
        }
        out[i] = r;
    }
}

// ---------------- CSR build ----------------
__global__ void zero_kernel(int* __restrict__ p, int n) {
    int i = blockIdx.x * blockDim.x + threadIdx.x;
    if (i < n) p[i] = 0;
}

__global__ void hist_kernel(const int* __restrict__ dstI, int* __restrict__ counts, int E) {
    int i = blockIdx.x * blockDim.x + threadIdx.x;
    if (i < E) atomicAdd(&counts[dstI[i]], 1);
}

// single-block exclusive scan (N=100k -> 98 chunks of 1024; wave shfl scan)
__global__ __launch_bounds__(1024) void scan_kernel(const int* __restrict__ counts,
                                                    int* __restrict__ offsets,
                                                    int* __restrict__ nextp, int N) {
    __shared__ int wsum[16];
    __shared__ int carry_s;
    const int tid = threadIdx.x, lane = tid & 63, wid = tid >> 6;
    if (tid == 0) carry_s = 0;
    __syncthreads();
    for (int base = 0; base < N; base += 1024) {
        int i = base + tid;
        int v = (i < N) ? counts[i] : 0;
        int incl = v;
#pragma unroll
        for (int m = 1; m < 64; m <<= 1) {
            int t = __shfl_up(incl, m, 64);
            if (lane >= m) incl += t;
        }
        if (lane == 63) wsum[wid] = incl;
        __syncthreads();
        int woff = 0;
#pragma unroll
        for (int k = 0; k < 16; ++k) woff += (k < wid) ? wsum[k] : 0;
        int carry = carry_s;
        int excl = carry + woff + incl - v;
        if (i < N) { offsets[i] = excl; nextp[i] = excl; }
        __syncthreads();
        if (tid == 1023) carry_s = excl + v;
        __syncthreads();
    }
    if (tid == 0) offsets[N] = carry_s;
}

__global__ void scatter_kernel(const int* __restrict__ srcI, const int* __restrict__ dstI,
                               int* __restrict__ nextp,
                               int* __restrict__ e_s, int* __restrict__ src_s,
                               int* __restrict__ dst_g, int E) {
    int i = blockIdx.x * blockDim.x + threadIdx.x;
    if (i < E) {
        int d = dstI[i];
        int p = atomicAdd(&nextp[d], 1);
        e_s[p] = i;
        src_s[p] = srcI[i];
        dst_g[p] = d;
    }
}

// ---------------- CSR edge kernel ----------------
__global__ __launch_bounds__(256) void edge_kernel_csr(
    const float* __restrict__ x,   const float* __restrict__ pos,
    const float* __restrict__ nrm, const float* __restrict__ ea,
    const float* __restrict__ W1,  const float* __restrict__ b1,
    const float* __restrict__ g1,  const float* __restrict__ be1,
    const float* __restrict__ W2,  const float* __restrict__ b2,
    const float* __restrict__ g2,  const float* __restrict__ be2,
    const int* __restrict__ e_s,   const int* __restrict__ src_s,
    const int* __restrict__ dst_g,
    unsigned* __restrict__ out, int E, int ntiles, int tilesPerBlock)
{
    __shared__ _Float16 W1t[48][LDK];
    __shared__ _Float16 W2t[128][LDK];
    __shared__ _Float16 msgA[64][LDK];   // msg; h1 aliased after GEMM1
    __shared__ _Float16 h2w[64][LDH];    // LN2 output staging for segment walk
    __shared__ int dstL[64];

    const int lane = threadIdx.x & 63;
    const int w    = threadIdx.x >> 6;
    const int c16  = lane & 15;
    const int g    = lane >> 4;

    for (int i = threadIdx.x; i < 48 * 64; i += 256) {
        int n = i >> 6, k = i & 63;
        W1t[n][k] = (n < 47 && k < 47) ? (_Float16)W1[k * 47 + n] : (_Float16)0.f;
    }
    for (int i = threadIdx.x; i < 128 * 64; i += 256) {
        int n = i >> 6, k = i & 63;
        W2t[n][k] = (k < 47) ? (_Float16)W2[k * 128 + n] : (_Float16)0.f;
    }
    for (int i = threadIdx.x; i < 64 * LDK; i += 256)
        (&msgA[0][0])[i] = (_Float16)0.f;

    float b1v[3], g1v[3], be1v[3];
#pragma unroll
    for (int n = 0; n < 3; ++n) {
        int cc = n * 16 + c16;
        bool vld = cc < 47;
        b1v[n]  = vld ? b1[cc]  : 0.f;
        g1v[n]  = vld ? g1[cc]  : 0.f;
        be1v[n] = vld ? be1[cc] : 0.f;
    }
    float b2v[8], g2v[8], be2v[8];
#pragma unroll
    for (int n = 0; n < 8; ++n) {
        int cc = n * 16 + c16;
        b2v[n] = b2[cc]; g2v[n] = g2[cc]; be2v[n] = be2[cc];
    }
    __syncthreads();

    const int tbeg = blockIdx.x * tilesPerBlock;
    int tend = tbeg + tilesPerBlock;
    if (tend > ntiles) tend = ntiles;

    for (int tile = tbeg; tile < tend; ++tile) {
        const int base = tile * 64 + w * 16;   // CSR positions for this wave
        const int row0 = w * 16;

        // ---- Phase 1: build msg rows (wave-private) ----
#pragma unroll
        for (int i = 0; i < 8; ++i) {
            int el = i * 2 + (lane >> 5);
            int p  = base + el;
            int c  = lane & 31;
            float v = 0.f;
            if (p < E) { int s = src_s[p]; v = x[(size_t)s * 32 + c]; }
            msgA[row0 + el][c] = (_Float16)v;
        }
        if (lane < 44) {
            int eg = lane / 11, c = lane - eg * 11;
#pragma unroll
            for (int i = 0; i < 4; ++i) {
                int el = i * 4 + eg;
                int p  = base + el;
                float v = 0.f;
                if (p < E) { int e = e_s[p]; v = ea[(size_t)e * 11 + c]; }
                msgA[row0 + el][36 + c] = (_Float16)v;
            }
        }
        if (lane < 48) {
            int el = c16;
            int p  = base + el;
            bool vld = p < E;
            int s = 0, d = 0;
            if (vld) { s = src_s[p]; d = dst_g[p]; }
            float pix = pos[d * 3 + 0], piy = pos[d * 3 + 1], piz = pos[d * 3 + 2];
            float pjx = pos[s * 3 + 0], pjy = pos[s * 3 + 1], pjz = pos[s * 3 + 2];
            float nix = nrm[d * 3 + 0], niy = nrm[d * 3 + 1], niz = nrm[d * 3 + 2];
            float njx = nrm[s * 3 + 0], njy = nrm[s * 3 + 1], njz = nrm[s * 3 + 2];
            float px = pjx - pix, py = pjy - piy, pz = pjz - piz;
            float v1x, v1y, v1z, v2x, v2y, v2z;
            if (g == 0)      { v1x = nix; v1y = niy; v1z = niz; v2x = px;  v2y = py;  v2z = pz;  }
            else if (g == 1) { v1x = njx; v1y = njy; v1z = njz; v2x = px;  v2y = py;  v2z = pz;  }
            else             { v1x = nix; v1y = niy; v1z = niz; v2x = njx; v2y = njy; v2z = njz; }
            float cx = v1y * v2z - v1z * v2y;
            float cy = v1z * v2x - v1x * v2z;
            float cz = v1x * v2y - v1y * v2x;
            float ang = atan2f(sqrtf(cx * cx + cy * cy + cz * cz),
                               v1x * v2x + v1y * v2y + v1z * v2z);
            msgA[row0 + el][33 + g] = (_Float16)ang;
            if (g == 0) {
                msgA[row0 + el][32] = (_Float16)sqrtf(px * px + py * py + pz * pz);
                dstL[row0 + el] = vld ? d : -1;
            }
        }

        // ---- Phase 2: GEMM1 + LN1 (h1 back into msgA) ----
        f32x4 acc1[3];
#pragma unroll
        for (int n = 0; n < 3; ++n) acc1[n] = (f32x4){0.f, 0.f, 0.f, 0.f};
#pragma unroll
        for (int ks = 0; ks < 2; ++ks) {
            f16x8 a = *(const f16x8*)&msgA[row0 + c16][ks * 32 + g * 8];
#pragma unroll
            for (int n = 0; n < 3; ++n) {
                f16x8 b = *(const f16x8*)&W1t[n * 16 + c16][ks * 32 + g * 8];
                acc1[n] = __builtin_amdgcn_mfma_f32_16x16x32_f16(a, b, acc1[n], 0, 0, 0);
            }
        }
#pragma unroll
        for (int q = 0; q < 4; ++q) {
            float t0 = fmaxf(acc1[0][q] + b1v[0], 0.f);
            float t1 = fmaxf(acc1[1][q] + b1v[1], 0.f);
            float t2 = fmaxf(acc1[2][q] + b1v[2], 0.f);
            float s = t0 + t1 + t2;
            float s2 = t0 * t0 + t1 * t1 + t2 * t2;
#pragma unroll
            for (int m = 1; m < 16; m <<= 1) {
                s  += __shfl_xor(s,  m, 64);
                s2 += __shfl_xor(s2, m, 64);
            }
            float mu  = s * (1.f / 47.f);
            float var = s2 * (1.f / 47.f) - mu * mu;
            float rs  = rsqrtf(var + 1e-5f);
            int r = row0 + 4 * g + q;
            msgA[r][c16]      = (_Float16)((t0 - mu) * rs * g1v[0] + be1v[0]);
            msgA[r][16 + c16] = (_Float16)((t1 - mu) * rs * g1v[1] + be1v[1]);
            msgA[r][32 + c16] = (_Float16)((t2 - mu) * rs * g1v[2] + be1v[2]);
        }

        // ---- Phase 3: GEMM2 + LN2 -> h2w ----
        f32x4 acc2[8];
#pragma unroll
        for (int n = 0; n < 8; ++n) acc2[n] = (f32x4){0.f, 0.f, 0.f, 0.f};
#pragma unroll
        for (int ks = 0; ks < 2; ++ks) {
            f16x8 a = *(const f16x8*)&msgA[row0 + c16][ks * 32 + g * 8];
#pragma unroll
            for (int n = 0; n < 8; ++n) {
                f16x8 b = *(const f16x8*)&W2t[n * 16 + c16][ks * 32 + g * 8];
                acc2[n] = __builtin_amdgcn_mfma_f32_16x16x32_f16(a, b, acc2[n], 0, 0, 0);
            }
        }
#pragma unroll
        for (int q = 0; q < 4; ++q) {
            float t[8];
            float s = 0.f, s2 = 0.f;
#pragma unroll
            for (int n = 0; n < 8; ++n) {
                t[n] = fmaxf(acc2[n][q] + b2v[n], 0.f);
                s += t[n]; s2 += t[n] * t[n];
            }
#pragma unroll
            for (int m = 1; m < 16; m <<= 1) {
                s  += __shfl_xor(s,  m, 64);
                s2 += __shfl_xor(s2, m, 64);
            }
            float mu  = s * (1.f / 128.f);
            float var = s2 * (1.f / 128.f) - mu * mu;
            float rs  = rsqrtf(var + 1e-5f);
            int r = row0 + 4 * g + q;
#pragma unroll
            for (int n = 0; n < 8; ++n) {
                float o = (t[n] - mu) * rs * g2v[n] + be2v[n];
                h2w[r][n * 16 + c16] = (_Float16)o;
            }
        }

        // ---- Phase 4: segmented max walk (wave-private, dst-sorted rows) ----
        // lane owns output cols 2*lane, 2*lane+1. Interior segments (start>0 &&
        // end<15) are touched by no other window -> plain store; boundary
        // segments use atomicMax.
        {
            float m0 = -INFINITY, m1 = -INFINITY;
            int segStart = 0;
            int dcur = dstL[row0];
            for (int r = 0; r < 16; ++r) {
                f16x2 pk = *(const f16x2*)&h2w[row0 + r][lane * 2];
                m0 = fmaxf(m0, (float)pk[0]);
                m1 = fmaxf(m1, (float)pk[1]);
                int dnext = (r < 15) ? dstL[row0 + r + 1] : -2;
                if (dnext != dcur) {
                    if (dcur >= 0) {
                        unsigned e0 = fenc(m0), e1 = fenc(m1);
                        unsigned* orow = out + (size_t)dcur * 128 + lane * 2;
                        if (segStart > 0 && r < 15) {
                            unsigned long long pk2 =
                                ((unsigned long long)e1 << 32) | (unsigned long long)e0;
                            *(unsigned long long*)orow = pk2;
                        } else {
                            atomicMax(orow,     e0);
                            atomicMax(orow + 1, e1);
                        }
                    }
                    m0 = -INFINITY; m1 = -INFINITY;
                    segStart = r + 1; dcur = dnext;
                }
            }
        }
    }
}

// ---------------- fallback (round-2): direct atomics, no CSR ----------------
__global__ __launch_bounds__(256) void edge_kernel_atomic(
    const float* __restrict__ x,   const float* __restrict__ pos,
    const float* __restrict__ nrm, const float* __restrict__ ea,
    const float* __restrict__ W1,  const float* __restrict__ b1,
    const float* __restrict__ g1,  const float* __restrict__ be1,
    const float* __restrict__ W2,  const float* __restrict__ b2,
    const float* __restrict__ g2,  const float* __restrict__ be2,
    const int* __restrict__ srcI,  const int* __restrict__ dstI,
    unsigned* __restrict__ out, int E, int ntiles)
{
    __shared__ _Float16 W1t[48][LDK];
    __shared__ _Float16 W2t[128][LDK];
    __shared__ _Float16 msgA[64][LDK];
    __shared__ int dst_s[64];

    const int lane = threadIdx.x & 63;
    const int w    = threadIdx.x >> 6;
    const int c16  = lane & 15;
    const int g    = lane >> 4;

    for (int i = threadIdx.x; i < 48 * 64; i += 256) {
        int n = i >> 6, k = i & 63;
        W1t[n][k] = (n < 47 && k < 47) ? (_Float16)W1[k * 47 + n] : (_Float16)0.f;
    }
    for (int i = threadIdx.x; i < 128 * 64; i += 256) {
        int n = i >> 6, k = i & 63;
        W2t[n][k] = (k < 47) ? (_Float16)W2[k * 128 + n] : (_Float16)0.f;
    }
    for (int i = threadIdx.x; i < 64 * LDK; i += 256)
        (&msgA[0][0])[i] = (_Float16)0.f;

    float b1v[3], g1v[3], be1v[3];
#pragma unroll
    for (int n = 0; n < 3; ++n) {
        int cc = n * 16 + c16;
        bool vld = cc < 47;
        b1v[n]  = vld ? b1[cc]  : 0.f;
        g1v[n]  = vld ? g1[cc]  : 0.f;
        be1v[n] = vld ? be1[cc] : 0.f;
    }
    float b2v[8], g2v[8], be2v[8];
#pragma unroll
    for (int n = 0; n < 8; ++n) {
        int cc = n * 16 + c16;
        b2v[n] = b2[cc]; g2v[n] = g2[cc]; be2v[n] = be2[cc];
    }
    __syncthreads();

    for (int tile = blockIdx.x; tile < ntiles; tile += gridDim.x) {
        const int base = tile * 64 + w * 16;
        const int row0 = w * 16;
#pragma unroll
        for (int i = 0; i < 8; ++i) {
            int el = i * 2 + (lane >> 5);
            int e  = base + el;
            int c  = lane & 31;
            float v = 0.f;
            if (e < E) v = x[(size_t)srcI[e] * 32 + c];
            msgA[row0 + el][c] = (_Float16)v;
        }
        if (lane < 44) {
            int eg = lane / 11, c = lane - eg * 11;
#pragma unroll
            for (int i = 0; i < 4; ++i) {
                int el = i * 4 + eg;
                int e  = base + el;
                float v = 0.f;
                if (e < E) v = ea[(size_t)e * 11 + c];
                msgA[row0 + el][36 + c] = (_Float16)v;
            }
        }
        if (lane < 48) {
            int el = c16;
            int e  = base + el;
            int s = 0, d = 0;
            bool vld = e < E;
            if (vld) { s = srcI[e]; d = dstI[e]; }
            float pix = pos[d * 3 + 0], piy = pos[d * 3 + 1], piz = pos[d * 3 + 2];
            float pjx = pos[s * 3 + 0], pjy = pos[s * 3 + 1], pjz = pos[s * 3 + 2];
            float nix = nrm[d * 3 + 0], niy = nrm[d * 3 + 1], niz = nrm[d * 3 + 2];
            float njx = nrm[s * 3 + 0], njy = nrm[s * 3 + 1], njz = nrm[s * 3 + 2];
            float px = pjx - pix, py = pjy - piy, pz = pjz - piz;
            float v1x, v1y, v1z, v2x, v2y, v2z;
            if (g == 0)      { v1x = nix; v1y = niy; v1z = niz; v2x = px;  v2y = py;  v2z = pz;  }
            else if (g == 1) { v1x = njx; v1y = njy; v1z = njz; v2x = px;  v2y = py;  v2z = pz;  }
            else             { v1x = nix; v1y = niy; v1z = niz; v2x = njx; v2y = njy; v2z = njz; }
            float cx = v1y * v2z - v1z * v2y;
            float cy = v1z * v2x - v1x * v2z;
            float cz = v1x * v2y - v1y * v2x;
            float ang = atan2f(sqrtf(cx * cx + cy * cy + cz * cz),
                               v1x * v2x + v1y * v2y + v1z * v2z);
            msgA[row0 + el][33 + g] = (_Float16)ang;
            if (g == 0) {
                msgA[row0 + el][32] = (_Float16)sqrtf(px * px + py * py + pz * pz);
                dst_s[row0 + el] = vld ? d : -1;
            }
        }

        f32x4 acc1[3];
#pragma unroll
        for (int n = 0; n < 3; ++n) acc1[n] = (f32x4){0.f, 0.f, 0.f, 0.f};
#pragma unroll
        for (int ks = 0; ks < 2; ++ks) {
            f16x8 a = *(const f16x8*)&msgA[row0 + c16][ks * 32 + g * 8];
#pragma unroll
            for (int n = 0; n < 3; ++n) {
                f16x8 b = *(const f16x8*)&W1t[n * 16 + c16][ks * 32 + g * 8];
                acc1[n] = __builtin_amdgcn_mfma_f32_16x16x32_f16(a, b, acc1[n], 0, 0, 0);
            }
        }
#pragma unroll
        for (int q = 0; q < 4; ++q) {
            float t0 = fmaxf(acc1[0][q] + b1v[0], 0.f);
            float t1 = fmaxf(acc1[1][q] + b1v[1], 0.f);
            float t2 = fmaxf(acc1[2][q] + b1v[2], 0.f);
            float s = t0 + t1 + t2;
            float s2 = t0 * t0 + t1 * t1 + t2 * t2;
#pragma unroll
            for (int m = 1; m < 16; m <<= 1) {
                s  += __shfl_xor(s,  m, 64);
                s2 += __shfl_xor(s2, m, 64);
            }
            float mu  = s * (1.f / 47.f);
            float var = s2 * (1.f / 47.f) - mu * mu;
            float rs  = rsqrtf(var + 1e-5f);
            int r = row0 + 4 * g + q;
            msgA[r][c16]      = (_Float16)((t0 - mu) * rs * g1v[0] + be1v[0]);
            msgA[r][16 + c16] = (_Float16)((t1 - mu) * rs * g1v[1] + be1v[1]);
            msgA[r][32 + c16] = (_Float16)((t2 - mu) * rs * g1v[2] + be1v[2]);
        }

        f32x4 acc2[8];
#pragma unroll
        for (int n = 0; n < 8; ++n) acc2[n] = (f32x4){0.f, 0.f, 0.f, 0.f};
#pragma unroll
        for (int ks = 0; ks < 2; ++ks) {
            f16x8 a = *(const f16x8*)&msgA[row0 + c16][ks * 32 + g * 8];
#pragma unroll
            for (int n = 0; n < 8; ++n) {
                f16x8 b = *(const f16x8*)&W2t[n * 16 + c16][ks * 32 + g * 8];
                acc2[n] = __builtin_amdgcn_mfma_f32_16x16x32_f16(a, b, acc2[n], 0, 0, 0);
            }
        }
        int4 dd = *(const int4*)&dst_s[row0 + 4 * g];
#pragma unroll
        for (int q = 0; q < 4; ++q) {
            float t[8];
            float s = 0.f, s2 = 0.f;
#pragma unroll
            for (int n = 0; n < 8; ++n) {
                t[n] = fmaxf(acc2[n][q] + b2v[n], 0.f);
                s += t[n]; s2 += t[n] * t[n];
            }
#pragma unroll
            for (int m = 1; m < 16; m <<= 1) {
                s  += __shfl_xor(s,  m, 64);
                s2 += __shfl_xor(s2, m, 64);
            }
            float mu  = s * (1.f / 128.f);
            float var = s2 * (1.f / 128.f) - mu * mu;
            float rs  = rsqrtf(var + 1e-5f);
            int d = (&dd.x)[q];
            if (d >= 0) {
                unsigned* orow = out + (size_t)d * 128u;
#pragma unroll
                for (int n = 0; n < 8; ++n) {
                    float o = (t[n] - mu) * rs * g2v[n] + be2v[n];
                    atomicMax(orow + n * 16 + c16, fenc(o));
                }
            }
        }
    }
}

extern "C" void kernel_launch(void* const* d_in, const int* in_sizes, int n_in,
                              void* d_out, int out_size, void* d_ws, size_t ws_size,
                              hipStream_t stream) {
    const float* x   = (const float*)d_in[0];
    const float* pos = (const float*)d_in[1];
    const float* nrm = (const float*)d_in[2];
    const float* ea  = (const float*)d_in[3];
    const float* W1  = (const float*)d_in[4];
    const float* b1  = (const float*)d_in[5];
    const float* g1  = (const float*)d_in[6];
    const float* be1 = (const float*)d_in[7];
    const float* W2  = (const float*)d_in[8];
    const float* b2  = (const float*)d_in[9];
    const float* g2  = (const float*)d_in[10];
    const float* be2 = (const float*)d_in[11];
    const int*   idx = (const int*)d_in[12];

    const int N = in_sizes[0] / 32;
    const int E = in_sizes[3] / 11;
    const int* srcI = idx;
    const int* dstI = idx + E;

    unsigned* outU = (unsigned*)d_out;
    const int n = N * 128;

    init_out_kernel<<<(n / 4 + 255) / 256, 256, 0, stream>>>(outU, n / 4);

    const size_t needed = (size_t)(3LL * N + 1 + 3LL * E) * 4;
    const int ntiles = (E + 63) / 64;

    if (ws_size >= needed) {
        int* counts  = (int*)d_ws;
        int* offsets = counts + N;
        int* nextp   = offsets + N + 1;
        int* e_s     = nextp + N;
        int* src_s   = e_s + E;
        int* dst_g   = src_s + E;

        zero_kernel<<<(N + 255) / 256, 256, 0, stream>>>(counts, N);
        hist_kernel<<<(E + 255) / 256, 256, 0, stream>>>(dstI, counts, E);
        scan_kernel<<<1, 1024, 0, stream>>>(counts, offsets, nextp, N);
        scatter_kernel<<<(E + 255) / 256, 256, 0, stream>>>(srcI, dstI, nextp,
                                                            e_s, src_s, dst_g, E);

        int grid = ntiles < 4096 ? ntiles : 4096;
        int tpb  = (ntiles + grid - 1) / grid;
        edge_kernel_csr<<<grid, 256, 0, stream>>>(x, pos, nrm, ea,
                                                  W1, b1, g1, be1,
                                                  W2, b2, g2, be2,
                                                  e_s, src_s, dst_g,
                                                  outU, E, ntiles, tpb);
    } else {
        int grid = ntiles < 4096 ? ntiles : 4096;
        edge_kernel_atomic<<<grid, 256, 0, stream>>>(x, pos, nrm, ea,
                                                     W1, b1, g1, be1,
                                                     W2, b2, g2, be2,
                                                     srcI, dstI, outU, E, ntiles);
    }

    finalize_out_kernel<<<(n + 255) / 256, 256, 0, stream>>>((float*)d_out, n);
}

// Round 5
// 1409.178 us; speedup vs baseline: 1.1251x; 1.0189x over previous
//
#include <hip/hip_runtime.h>
#include <cstdint>
#include <cstddef>

// ---------------------------------------------------------------------------
// DockPointNet fused edge-MLP + segment-max, f16 MFMA + CSR counting sort.
// Round 5: (1) 8-wave blocks -> 2 blocks/CU, 16 waves/CU (was 12, LDS-capped);
// (2) XOR k-block swizzle on msg/W LDS (round-4 profile: 23M bank-conflict
// cycles = 8-way conflicts on every MFMA fragment ds_read_b128);
// (3) cross-tile register prefetch of x/ea/pos/nrm gathers (hide HBM/L3
// latency under GEMM+LN+walk compute).
// ---------------------------------------------------------------------------

typedef _Float16 f16x8 __attribute__((ext_vector_type(8)));
typedef _Float16 f16x2 __attribute__((ext_vector_type(2)));
typedef float    f32x4 __attribute__((ext_vector_type(4)));

#define ENC_NEGINF 0x007FFFFFu   // fenc(-inf)
#define LDK 64                   // msg/W row stride (f16), 128B: swizzle mandatory
#define LDH 132                  // h2 row stride (f16)

// XOR swizzle: permute 8-f16 blocks within a 64-f16 row by row&7.
// Row stride 128B == 32 banks, so bank = f(swizzled col) only; for frag reads
// (fixed col, varying row) the XOR spreads rows across bank groups.
__device__ __forceinline__ int swz(int row, int col) {
    return (col & 7) | ((((col >> 3) ^ row) & 7) << 3);
}

__device__ __forceinline__ unsigned fenc(float f) {
    unsigned u = __float_as_uint(f);
    return (u & 0x80000000u) ? ~u : (u | 0x80000000u);
}

__global__ void init_out_kernel(unsigned* __restrict__ out, int n4) {
    int i = blockIdx.x * blockDim.x + threadIdx.x;
    if (i < n4)
        ((uint4*)out)[i] = make_uint4(ENC_NEGINF, ENC_NEGINF, ENC_NEGINF, ENC_NEGINF);
}

__global__ void finalize_out_kernel(float* __restrict__ out, int n) {
    int i = blockIdx.x * blockDim.x + threadIdx.x;
    if (i < n) {
        unsigned k = __float_as_uint(out[i]);
        float r;
        if (k == ENC_NEGINF) r = 0.0f;
        else {
            unsigned u = (k & 0x80000000u) ? (k ^ 0x80000000u) : ~k;
            r = __uint_as_float(u);
        }
        out[i] = r;
    }
}

// ---------------- CSR build ----------------
__global__ void zero_kernel(int* __restrict__ p, int n) {
    int i = blockIdx.x * blockDim.x + threadIdx.x;
    if (i < n) p[i] = 0;
}

__global__ void hist_kernel(const int* __restrict__ dstI, int* __restrict__ counts, int E) {
    int i = blockIdx.x * blockDim.x + threadIdx.x;
    if (i < E) atomicAdd(&counts[dstI[i]], 1);
}

__global__ __launch_bounds__(1024) void scan_kernel(const int* __restrict__ counts,
                                                    int* __restrict__ nextp, int N) {
    __shared__ int wsum[16];
    __shared__ int carry_s;
    const int tid = threadIdx.x, lane = tid & 63, wid = tid >> 6;
    if (tid == 0) carry_s = 0;
    __syncthreads();
    for (int base = 0; base < N; base += 1024) {
        int i = base + tid;
        int v = (i < N) ? counts[i] : 0;
        int incl = v;
#pragma unroll
        for (int m = 1; m < 64; m <<= 1) {
            int t = __shfl_up(incl, m, 64);
            if (lane >= m) incl += t;
        }
        if (lane == 63) wsum[wid] = incl;
        __syncthreads();
        int woff = 0;
#pragma unroll
        for (int k = 0; k < 16; ++k) woff += (k < wid) ? wsum[k] : 0;
        int excl = carry_s + woff + incl - v;
        if (i < N) nextp[i] = excl;
        __syncthreads();
        if (tid == 1023) carry_s = excl + v;
        __syncthreads();
    }
}

__global__ void scatter_kernel(const int* __restrict__ srcI, const int* __restrict__ dstI,
                               int* __restrict__ nextp,
                               int2* __restrict__ se, int* __restrict__ dst_g, int E) {
    int i = blockIdx.x * blockDim.x + threadIdx.x;
    if (i < E) {
        int d = dstI[i];
        int p = atomicAdd(&nextp[d], 1);
        se[p] = make_int2(srcI[i], i);
        dst_g[p] = d;
    }
}

// ---------------- CSR edge kernel: 8 waves/block ----------------
__global__ __launch_bounds__(512, 4) void edge_kernel_csr(
    const float* __restrict__ x,   const float* __restrict__ pos,
    const float* __restrict__ nrm, const float* __restrict__ ea,
    const float* __restrict__ W1,  const float* __restrict__ b1,
    const float* __restrict__ g1,  const float* __restrict__ be1,
    const float* __restrict__ W2,  const float* __restrict__ b2,
    const float* __restrict__ g2,  const float* __restrict__ be2,
    const int2* __restrict__ se,   const int* __restrict__ dst_g,
    unsigned* __restrict__ out, int E, int ntiles, int tilesPerBlock)
{
    __shared__ _Float16 W1t[48][LDK];     // 6.0 KB  (swizzled [n][k])
    __shared__ _Float16 W2t[128][LDK];    // 16.0 KB
    __shared__ _Float16 msgA[128][LDK];   // 16.0 KB (msg; h1 aliased after GEMM1)
    __shared__ _Float16 h2w[128][LDH];    // 33.0 KB (linear; walk reads conflict-free)
    __shared__ int dstL[128];

    const int lane = threadIdx.x & 63;
    const int w    = threadIdx.x >> 6;   // 0..7
    const int c16  = lane & 15;
    const int g    = lane >> 4;
    const int row0 = w * 16;

    // ---- stage weights (f16, transposed, zero-padded, swizzled) ----
    for (int i = threadIdx.x; i < 48 * 64; i += 512) {
        int n = i >> 6, k = i & 63;
        W1t[n][swz(n, k)] = (n < 47 && k < 47) ? (_Float16)W1[k * 47 + n] : (_Float16)0.f;
    }
    for (int i = threadIdx.x; i < 128 * 64; i += 512) {
        int n = i >> 6, k = i & 63;
        W2t[n][swz(n, k)] = (k < 47) ? (_Float16)W2[k * 128 + n] : (_Float16)0.f;
    }
    for (int i = threadIdx.x; i < 128 * LDK; i += 512)
        (&msgA[0][0])[i] = (_Float16)0.f;

    // ---- per-lane LN params ----
    float b1v[3], g1v[3], be1v[3];
#pragma unroll
    for (int n = 0; n < 3; ++n) {
        int cc = n * 16 + c16;
        bool vld = cc < 47;
        b1v[n]  = vld ? b1[cc]  : 0.f;
        g1v[n]  = vld ? g1[cc]  : 0.f;
        be1v[n] = vld ? be1[cc] : 0.f;
    }
    float b2v[8], g2v[8], be2v[8];
#pragma unroll
    for (int n = 0; n < 8; ++n) {
        int cc = n * 16 + c16;
        b2v[n] = b2[cc]; g2v[n] = g2[cc]; be2v[n] = be2[cc];
    }
    __syncthreads();

    // ---- prefetch lane roles ----
    const int xr = lane >> 2;            // x gather: row, 4 lanes/row
    const int xc = (lane & 3) * 8;       //           8 channels each
    const int eg = lane / 11, ec = lane - eg * 11;   // ea: lanes<44
    const bool ea_act  = lane < 44;
    const bool geo_act = lane < 48;

    float4 pxa, pxb;
    float  pea[4];
    float  pgp[12];
    int    pd = -1;

    auto prefetch = [&](int tile) {
        const int base = tile * 128 + row0;
        {
            int p = base + xr;
            int s = (p < E) ? se[p].x : 0;
            const float4* xp = (const float4*)(x + (size_t)s * 32 + xc);
            pxa = xp[0]; pxb = xp[1];
        }
        if (ea_act) {
#pragma unroll
            for (int i = 0; i < 4; ++i) {
                int p = base + i * 4 + eg;
                int e = (p < E) ? se[p].y : 0;
                pea[i] = ea[(size_t)e * 11 + ec];
            }
        }
        if (geo_act) {
            int p = base + c16;
            bool v = p < E;
            int s = v ? se[p].x : 0;
            int d = v ? dst_g[p] : 0;
            pd = v ? d : -1;
#pragma unroll
            for (int k = 0; k < 3; ++k) {
                pgp[0 + k] = pos[d * 3 + k];
                pgp[3 + k] = pos[s * 3 + k];
                pgp[6 + k] = nrm[d * 3 + k];
                pgp[9 + k] = nrm[s * 3 + k];
            }
        }
    };

    auto commit = [&](int tile) {
        const int base = tile * 128 + row0;
        {   // x row: one 16B swizzle-aligned LDS store
            bool v = (base + xr) < E;
            int r = row0 + xr;
            f16x8 hv;
            hv[0] = (_Float16)(v ? pxa.x : 0.f); hv[1] = (_Float16)(v ? pxa.y : 0.f);
            hv[2] = (_Float16)(v ? pxa.z : 0.f); hv[3] = (_Float16)(v ? pxa.w : 0.f);
            hv[4] = (_Float16)(v ? pxb.x : 0.f); hv[5] = (_Float16)(v ? pxb.y : 0.f);
            hv[6] = (_Float16)(v ? pxb.z : 0.f); hv[7] = (_Float16)(v ? pxb.w : 0.f);
            *(f16x8*)&msgA[r][swz(r, xc)] = hv;
        }
        if (ea_act) {
#pragma unroll
            for (int i = 0; i < 4; ++i) {
                bool v = (base + i * 4 + eg) < E;
                int r = row0 + i * 4 + eg;
                msgA[r][swz(r, 36 + ec)] = (_Float16)(v ? pea[i] : 0.f);
            }
        }
        if (geo_act) {
            int r = row0 + c16;
            float px = pgp[3] - pgp[0], py = pgp[4] - pgp[1], pz = pgp[5] - pgp[2];
            float v1x, v1y, v1z, v2x, v2y, v2z;
            if (g == 0)      { v1x = pgp[6]; v1y = pgp[7];  v1z = pgp[8];
                               v2x = px;     v2y = py;      v2z = pz; }
            else if (g == 1) { v1x = pgp[9]; v1y = pgp[10]; v1z = pgp[11];
                               v2x = px;     v2y = py;      v2z = pz; }
            else             { v1x = pgp[6]; v1y = pgp[7];  v1z = pgp[8];
                               v2x = pgp[9]; v2y = pgp[10]; v2z = pgp[11]; }
            float cx = v1y * v2z - v1z * v2y;
            float cy = v1z * v2x - v1x * v2z;
            float cz = v1x * v2y - v1y * v2x;
            float ang = atan2f(sqrtf(cx * cx + cy * cy + cz * cz),
                               v1x * v2x + v1y * v2y + v1z * v2z);
            msgA[r][swz(r, 33 + g)] = (_Float16)ang;
            if (g == 0) {
                msgA[r][swz(r, 32)] = (_Float16)sqrtf(px * px + py * py + pz * pz);
                dstL[r] = pd;
            }
        }
    };

    const int tbeg = blockIdx.x * tilesPerBlock;
    int tend = tbeg + tilesPerBlock;
    if (tend > ntiles) tend = ntiles;
    if (tbeg >= tend) return;

    prefetch(tbeg);

    for (int tile = tbeg; tile < tend; ++tile) {
        commit(tile);                         // regs -> LDS (+ angle VALU)
        if (tile + 1 < tend) prefetch(tile + 1);  // issue next gathers now

        // ---- GEMM1 (16x48) + LN1 -> h1 back into msgA ----
        f32x4 acc1[3];
#pragma unroll
        for (int n = 0; n < 3; ++n) acc1[n] = (f32x4){0.f, 0.f, 0.f, 0.f};
#pragma unroll
        for (int ks = 0; ks < 2; ++ks) {
            int ar = row0 + c16;
            f16x8 a = *(const f16x8*)&msgA[ar][swz(ar, ks * 32 + g * 8)];
#pragma unroll
            for (int n = 0; n < 3; ++n) {
                int br = n * 16 + c16;
                f16x8 b = *(const f16x8*)&W1t[br][swz(br, ks * 32 + g * 8)];
                acc1[n] = __builtin_amdgcn_mfma_f32_16x16x32_f16(a, b, acc1[n], 0, 0, 0);
            }
        }
#pragma unroll
        for (int q = 0; q < 4; ++q) {
            float t0 = fmaxf(acc1[0][q] + b1v[0], 0.f);
            float t1 = fmaxf(acc1[1][q] + b1v[1], 0.f);
            float t2 = fmaxf(acc1[2][q] + b1v[2], 0.f);   // col 47 -> 0
            float s = t0 + t1 + t2;
            float s2 = t0 * t0 + t1 * t1 + t2 * t2;
#pragma unroll
            for (int m = 1; m < 16; m <<= 1) {
                s  += __shfl_xor(s,  m, 64);
                s2 += __shfl_xor(s2, m, 64);
            }
            float mu  = s * (1.f / 47.f);
            float var = s2 * (1.f / 47.f) - mu * mu;
            float rs  = rsqrtf(var + 1e-5f);
            int r = row0 + 4 * g + q;
            msgA[r][swz(r, c16)]      = (_Float16)((t0 - mu) * rs * g1v[0] + be1v[0]);
            msgA[r][swz(r, 16 + c16)] = (_Float16)((t1 - mu) * rs * g1v[1] + be1v[1]);
            msgA[r][swz(r, 32 + c16)] = (_Float16)((t2 - mu) * rs * g1v[2] + be1v[2]);
        }

        // ---- GEMM2 (16x128) + LN2 -> h2w ----
        f32x4 acc2[8];
#pragma unroll
        for (int n = 0; n < 8; ++n) acc2[n] = (f32x4){0.f, 0.f, 0.f, 0.f};
#pragma unroll
        for (int ks = 0; ks < 2; ++ks) {
            int ar = row0 + c16;
            f16x8 a = *(const f16x8*)&msgA[ar][swz(ar, ks * 32 + g * 8)];
#pragma unroll
            for (int n = 0; n < 8; ++n) {
                int br = n * 16 + c16;
                f16x8 b = *(const f16x8*)&W2t[br][swz(br, ks * 32 + g * 8)];
                acc2[n] = __builtin_amdgcn_mfma_f32_16x16x32_f16(a, b, acc2[n], 0, 0, 0);
            }
        }
#pragma unroll
        for (int q = 0; q < 4; ++q) {
            float t[8];
            float s = 0.f, s2 = 0.f;
#pragma unroll
            for (int n = 0; n < 8; ++n) {
                t[n] = fmaxf(acc2[n][q] + b2v[n], 0.f);
                s += t[n]; s2 += t[n] * t[n];
            }
#pragma unroll
            for (int m = 1; m < 16; m <<= 1) {
                s  += __shfl_xor(s,  m, 64);
                s2 += __shfl_xor(s2, m, 64);
            }
            float mu  = s * (1.f / 128.f);
            float var = s2 * (1.f / 128.f) - mu * mu;
            float rs  = rsqrtf(var + 1e-5f);
            int r = row0 + 4 * g + q;
#pragma unroll
            for (int n = 0; n < 8; ++n) {
                float o = (t[n] - mu) * rs * g2v[n] + be2v[n];
                h2w[r][n * 16 + c16] = (_Float16)o;
            }
        }

        // ---- segmented max walk (wave-private, dst-sorted rows) ----
        {
            float m0 = -INFINITY, m1 = -INFINITY;
            int segStart = 0;
            int dcur = dstL[row0];
#pragma unroll
            for (int r = 0; r < 16; ++r) {
                f16x2 pk = *(const f16x2*)&h2w[row0 + r][lane * 2];
                m0 = fmaxf(m0, (float)pk[0]);
                m1 = fmaxf(m1, (float)pk[1]);
                int dnext = (r < 15) ? dstL[row0 + r + 1] : -2;
                if (dnext != dcur) {
                    if (dcur >= 0) {
                        unsigned e0 = fenc(m0), e1 = fenc(m1);
                        unsigned* orow = out + (size_t)dcur * 128 + lane * 2;
                        if (segStart > 0 && r < 15) {
                            unsigned long long pk2 =
                                ((unsigned long long)e1 << 32) | (unsigned long long)e0;
                            *(unsigned long long*)orow = pk2;
                        } else {
                            atomicMax(orow,     e0);
                            atomicMax(orow + 1, e1);
                        }
                    }
                    m0 = -INFINITY; m1 = -INFINITY;
                    segStart = r + 1; dcur = dnext;
                }
            }
        }
    }
}

// ---------------- fallback: direct atomics, no CSR (round-2 form) ----------------
#define LDKF 72
__global__ __launch_bounds__(256) void edge_kernel_atomic(
    const float* __restrict__ x,   const float* __restrict__ pos,
    const float* __restrict__ nrm, const float* __restrict__ ea,
    const float* __restrict__ W1,  const float* __restrict__ b1,
    const float* __restrict__ g1,  const float* __restrict__ be1,
    const float* __restrict__ W2,  const float* __restrict__ b2,
    const float* __restrict__ g2,  const float* __restrict__ be2,
    const int* __restrict__ srcI,  const int* __restrict__ dstI,
    unsigned* __restrict__ out, int E, int ntiles)
{
    __shared__ _Float16 W1t[48][LDKF];
    __shared__ _Float16 W2t[128][LDKF];
    __shared__ _Float16 msgA[64][LDKF];
    __shared__ int dst_s[64];

    const int lane = threadIdx.x & 63;
    const int w    = threadIdx.x >> 6;
    const int c16  = lane & 15;
    const int g    = lane >> 4;

    for (int i = threadIdx.x; i < 48 * 64; i += 256) {
        int n = i >> 6, k = i & 63;
        W1t[n][k] = (n < 47 && k < 47) ? (_Float16)W1[k * 47 + n] : (_Float16)0.f;
    }
    for (int i = threadIdx.x; i < 128 * 64; i += 256) {
        int n = i >> 6, k = i & 63;
        W2t[n][k] = (k < 47) ? (_Float16)W2[k * 128 + n] : (_Float16)0.f;
    }
    for (int i = threadIdx.x; i < 64 * LDKF; i += 256)
        (&msgA[0][0])[i] = (_Float16)0.f;

    float b1v[3], g1v[3], be1v[3];
#pragma unroll
    for (int n = 0; n < 3; ++n) {
        int cc = n * 16 + c16;
        bool vld = cc < 47;
        b1v[n]  = vld ? b1[cc]  : 0.f;
        g1v[n]  = vld ? g1[cc]  : 0.f;
        be1v[n] = vld ? be1[cc] : 0.f;
    }
    float b2v[8], g2v[8], be2v[8];
#pragma unroll
    for (int n = 0; n < 8; ++n) {
        int cc = n * 16 + c16;
        b2v[n] = b2[cc]; g2v[n] = g2[cc]; be2v[n] = be2[cc];
    }
    __syncthreads();

    for (int tile = blockIdx.x; tile < ntiles; tile += gridDim.x) {
        const int base = tile * 64 + w * 16;
        const int row0 = w * 16;
#pragma unroll
        for (int i = 0; i < 8; ++i) {
            int el = i * 2 + (lane >> 5);
            int e  = base + el;
            int c  = lane & 31;
            float v = 0.f;
            if (e < E) v = x[(size_t)srcI[e] * 32 + c];
            msgA[row0 + el][c] = (_Float16)v;
        }
        if (lane < 44) {
            int eg = lane / 11, c = lane - eg * 11;
#pragma unroll
            for (int i = 0; i < 4; ++i) {
                int el = i * 4 + eg;
                int e  = base + el;
                float v = 0.f;
                if (e < E) v = ea[(size_t)e * 11 + c];
                msgA[row0 + el][36 + c] = (_Float16)v;
            }
        }
        if (lane < 48) {
            int el = c16;
            int e  = base + el;
            int s = 0, d = 0;
            bool vld = e < E;
            if (vld) { s = srcI[e]; d = dstI[e]; }
            float pix = pos[d * 3 + 0], piy = pos[d * 3 + 1], piz = pos[d * 3 + 2];
            float pjx = pos[s * 3 + 0], pjy = pos[s * 3 + 1], pjz = pos[s * 3 + 2];
            float nix = nrm[d * 3 + 0], niy = nrm[d * 3 + 1], niz = nrm[d * 3 + 2];
            float njx = nrm[s * 3 + 0], njy = nrm[s * 3 + 1], njz = nrm[s * 3 + 2];
            float px = pjx - pix, py = pjy - piy, pz = pjz - piz;
            float v1x, v1y, v1z, v2x, v2y, v2z;
            if (g == 0)      { v1x = nix; v1y = niy; v1z = niz; v2x = px;  v2y = py;  v2z = pz;  }
            else if (g == 1) { v1x = njx; v1y = njy; v1z = njz; v2x = px;  v2y = py;  v2z = pz;  }
            else             { v1x = nix; v1y = niy; v1z = niz; v2x = njx; v2y = njy; v2z = njz; }
            float cx = v1y * v2z - v1z * v2y;
            float cy = v1z * v2x - v1x * v2z;
            float cz = v1x * v2y - v1y * v2x;
            float ang = atan2f(sqrtf(cx * cx + cy * cy + cz * cz),
                               v1x * v2x + v1y * v2y + v1z * v2z);
            msgA[row0 + el][33 + g] = (_Float16)ang;
            if (g == 0) {
                msgA[row0 + el][32] = (_Float16)sqrtf(px * px + py * py + pz * pz);
                dst_s[row0 + el] = vld ? d : -1;
            }
        }

        f32x4 acc1[3];
#pragma unroll
        for (int n = 0; n < 3; ++n) acc1[n] = (f32x4){0.f, 0.f, 0.f, 0.f};
#pragma unroll
        for (int ks = 0; ks < 2; ++ks) {
            f16x8 a = *(const f16x8*)&msgA[row0 + c16][ks * 32 + g * 8];
#pragma unroll
            for (int n = 0; n < 3; ++n) {
                f16x8 b = *(const f16x8*)&W1t[n * 16 + c16][ks * 32 + g * 8];
                acc1[n] = __builtin_amdgcn_mfma_f32_16x16x32_f16(a, b, acc1[n], 0, 0, 0);
            }
        }
#pragma unroll
        for (int q = 0; q < 4; ++q) {
            float t0 = fmaxf(acc1[0][q] + b1v[0], 0.f);
            float t1 = fmaxf(acc1[1][q] + b1v[1], 0.f);
            float t2 = fmaxf(acc1[2][q] + b1v[2], 0.f);
            float s = t0 + t1 + t2;
            float s2 = t0 * t0 + t1 * t1 + t2 * t2;
#pragma unroll
            for (int m = 1; m < 16; m <<= 1) {
                s  += __shfl_xor(s,  m, 64);
                s2 += __shfl_xor(s2, m, 64);
            }
            float mu  = s * (1.f / 47.f);
            float var = s2 * (1.f / 47.f) - mu * mu;
            float rs  = rsqrtf(var + 1e-5f);
            int r = row0 + 4 * g + q;
            msgA[r][c16]      = (_Float16)((t0 - mu) * rs * g1v[0] + be1v[0]);
            msgA[r][16 + c16] = (_Float16)((t1 - mu) * rs * g1v[1] + be1v[1]);
            msgA[r][32 + c16] = (_Float16)((t2 - mu) * rs * g1v[2] + be1v[2]);
        }

        f32x4 acc2[8];
#pragma unroll
        for (int n = 0; n < 8; ++n) acc2[n] = (f32x4){0.f, 0.f, 0.f, 0.f};
#pragma unroll
        for (int ks = 0; ks < 2; ++ks) {
            f16x8 a = *(const f16x8*)&msgA[row0 + c16][ks * 32 + g * 8];
#pragma unroll
            for (int n = 0; n < 8; ++n) {
                f16x8 b = *(const f16x8*)&W2t[n * 16 + c16][ks * 32 + g * 8];
                acc2[n] = __builtin_amdgcn_mfma_f32_16x16x32_f16(a, b, acc2[n], 0, 0, 0);
            }
        }
        int4 dd = *(const int4*)&dst_s[row0 + 4 * g];
#pragma unroll
        for (int q = 0; q < 4; ++q) {
            float t[8];
            float s = 0.f, s2 = 0.f;
#pragma unroll
            for (int n = 0; n < 8; ++n) {
                t[n] = fmaxf(acc2[n][q] + b2v[n], 0.f);
                s += t[n]; s2 += t[n] * t[n];
            }
#pragma unroll
            for (int m = 1; m < 16; m <<= 1) {
                s  += __shfl_xor(s,  m, 64);
                s2 += __shfl_xor(s2, m, 64);
            }
            float mu  = s * (1.f / 128.f);
            float var = s2 * (1.f / 128.f) - mu * mu;
            float rs  = rsqrtf(var + 1e-5f);
            int d = (&dd.x)[q];
            if (d >= 0) {
                unsigned* orow = out + (size_t)d * 128u;
#pragma unroll
                for (int n = 0; n < 8; ++n) {
                    float o = (t[n] - mu) * rs * g2v[n] + be2v[n];
                    atomicMax(orow + n * 16 + c16, fenc(o));
                }
            }
        }
    }
}

extern "C" void kernel_launch(void* const* d_in, const int* in_sizes, int n_in,
                              void* d_out, int out_size, void* d_ws, size_t ws_size,
                              hipStream_t stream) {
    const float* x   = (const float*)d_in[0];
    const float* pos = (const float*)d_in[1];
    const float* nrm = (const float*)d_in[2];
    const float* ea  = (const float*)d_in[3];
    const float* W1  = (const float*)d_in[4];
    const float* b1  = (const float*)d_in[5];
    const float* g1  = (const float*)d_in[6];
    const float* be1 = (const float*)d_in[7];
    const float* W2  = (const float*)d_in[8];
    const float* b2  = (const float*)d_in[9];
    const float* g2  = (const float*)d_in[10];
    const float* be2 = (const float*)d_in[11];
    const int*   idx = (const int*)d_in[12];

    const int N = in_sizes[0] / 32;
    const int E = in_sizes[3] / 11;
    const int* srcI = idx;
    const int* dstI = idx + E;

    unsigned* outU = (unsigned*)d_out;
    const int n = N * 128;

    init_out_kernel<<<(n / 4 + 255) / 256, 256, 0, stream>>>(outU, n / 4);

    // ws layout: se[E] int2 | counts[N] | nextp[N] | dst_g[E]
    const size_t needed = (size_t)E * 8 + (size_t)(2LL * N + E) * 4;

    if (ws_size >= needed) {
        int2* se     = (int2*)d_ws;
        int*  counts = (int*)(se + E);
        int*  nextp  = counts + N;
        int*  dst_g  = nextp + N;

        zero_kernel<<<(N + 255) / 256, 256, 0, stream>>>(counts, N);
        hist_kernel<<<(E + 255) / 256, 256, 0, stream>>>(dstI, counts, E);
        scan_kernel<<<1, 1024, 0, stream>>>(counts, nextp, N);
        scatter_kernel<<<(E + 255) / 256, 256, 0, stream>>>(srcI, dstI, nextp,
                                                            se, dst_g, E);

        const int ntiles = (E + 127) / 128;
        int grid = ntiles < 1024 ? ntiles : 1024;
        int tpb  = (ntiles + grid - 1) / grid;
        edge_kernel_csr<<<grid, 512, 0, stream>>>(x, pos, nrm, ea,
                                                  W1, b1, g1, be1,
                                                  W2, b2, g2, be2,
                                                  se, dst_g,
                                                  outU, E, ntiles, tpb);
    } else {
        const int ntiles = (E + 63) / 64;
        int grid = ntiles < 4096 ? ntiles : 4096;
        edge_kernel_atomic<<<grid, 256, 0, stream>>>(x, pos, nrm, ea,
                                                     W1, b1, g1, be1,
                                                     W2, b2, g2, be2,
                                                     srcI, dstI, outU, E, ntiles);
    }

    finalize_out_kernel<<<(n + 255) / 256, 256, 0, stream>>>((float*)d_out, n);
}

// Round 6
// 919.518 us; speedup vs baseline: 1.7242x; 1.5325x over previous
//
#include <hip/hip_runtime.h>
#include <cstdint>
#include <cstddef>

// ---------------------------------------------------------------------------
// DockPointNet fused edge-MLP + segment-max, f16 MFMA + CSR counting sort.
// Round 6: (1) de-spill the edge kernel -- round-5's cross-tile prefetch
// lambdas kept 26 floats live across the whole compute region; compiler
// allocated 64 VGPRs and spilled (hbm_bytes tripled to 2.38 GB). Now gathers
// are issued inline at tile start, minimal live state. (2) multi-block scan
// (chunk-scan -> top-scan -> add) replaces the single-block scan.
// ---------------------------------------------------------------------------

typedef _Float16 f16x8 __attribute__((ext_vector_type(8)));
typedef _Float16 f16x2 __attribute__((ext_vector_type(2)));
typedef float    f32x4 __attribute__((ext_vector_type(4)));

#define ENC_NEGINF 0x007FFFFFu   // fenc(-inf)
#define LDK 64                   // msg/W row stride (f16), 128B: swizzle mandatory
#define LDH 132                  // h2 row stride (f16)

// XOR swizzle: permute 8-f16 blocks within a 64-f16 row by row&7.
__device__ __forceinline__ int swz(int row, int col) {
    return (col & 7) | ((((col >> 3) ^ row) & 7) << 3);
}

__device__ __forceinline__ unsigned fenc(float f) {
    unsigned u = __float_as_uint(f);
    return (u & 0x80000000u) ? ~u : (u | 0x80000000u);
}

__global__ void init_out_kernel(unsigned* __restrict__ out, int n4) {
    int i = blockIdx.x * blockDim.x + threadIdx.x;
    if (i < n4)
        ((uint4*)out)[i] = make_uint4(ENC_NEGINF, ENC_NEGINF, ENC_NEGINF, ENC_NEGINF);
}

__global__ void finalize_out_kernel(float* __restrict__ out, int n) {
    int i = blockIdx.x * blockDim.x + threadIdx.x;
    if (i < n) {
        unsigned k = __float_as_uint(out[i]);
        float r;
        if (k == ENC_NEGINF) r = 0.0f;
        else {
            unsigned u = (k & 0x80000000u) ? (k ^ 0x80000000u) : ~k;
            r = __uint_as_float(u);
        }
        out[i] = r;
    }
}

// ---------------- CSR build ----------------
__global__ void zero_kernel(int* __restrict__ p, int n) {
    int i = blockIdx.x * blockDim.x + threadIdx.x;
    if (i < n) p[i] = 0;
}

__global__ void hist_kernel(const int* __restrict__ dstI, int* __restrict__ counts, int E) {
    int i = blockIdx.x * blockDim.x + threadIdx.x;
    if (i < E) atomicAdd(&counts[dstI[i]], 1);
}

// exclusive scan of one 1024-chunk per block; optional per-block totals.
__global__ __launch_bounds__(1024) void scan_blk(const int* __restrict__ in,
                                                 int* __restrict__ outp,
                                                 int* __restrict__ bsums, int N) {
    __shared__ int wsum[16];
    const int tid = threadIdx.x, lane = tid & 63, wid = tid >> 6;
    int i = blockIdx.x * 1024 + tid;
    int v = (i < N) ? in[i] : 0;
    int incl = v;
#pragma unroll
    for (int m = 1; m < 64; m <<= 1) {
        int t = __shfl_up(incl, m, 64);
        if (lane >= m) incl += t;
    }
    if (lane == 63) wsum[wid] = incl;
    __syncthreads();
    int woff = 0;
#pragma unroll
    for (int k = 0; k < 16; ++k) woff += (k < wid) ? wsum[k] : 0;
    if (i < N) outp[i] = woff + incl - v;
    if (tid == 1023 && bsums != nullptr) bsums[blockIdx.x] = woff + incl;
}

__global__ __launch_bounds__(1024) void scan_add(int* __restrict__ outp,
                                                 const int* __restrict__ bsums, int N) {
    int i = blockIdx.x * 1024 + threadIdx.x;
    if (i < N) outp[i] += bsums[blockIdx.x];
}

__global__ void scatter_kernel(const int* __restrict__ srcI, const int* __restrict__ dstI,
                               int* __restrict__ nextp,
                               int2* __restrict__ se, int* __restrict__ dst_g, int E) {
    int i = blockIdx.x * blockDim.x + threadIdx.x;
    if (i < E) {
        int d = dstI[i];
        int p = atomicAdd(&nextp[d], 1);
        se[p] = make_int2(srcI[i], i);
        dst_g[p] = d;
    }
}

// ---------------- CSR edge kernel: 8 waves/block, no cross-tile prefetch ----
__global__ __launch_bounds__(512, 4) void edge_kernel_csr(
    const float* __restrict__ x,   const float* __restrict__ pos,
    const float* __restrict__ nrm, const float* __restrict__ ea,
    const float* __restrict__ W1,  const float* __restrict__ b1,
    const float* __restrict__ g1,  const float* __restrict__ be1,
    const float* __restrict__ W2,  const float* __restrict__ b2,
    const float* __restrict__ g2,  const float* __restrict__ be2,
    const int2* __restrict__ se,   const int* __restrict__ dst_g,
    unsigned* __restrict__ out, int E, int ntiles, int tilesPerBlock)
{
    __shared__ _Float16 W1t[48][LDK];     // 6.0 KB  (swizzled [n][k])
    __shared__ _Float16 W2t[128][LDK];    // 16.0 KB
    __shared__ _Float16 msgA[128][LDK];   // 16.0 KB (msg; h1 aliased after GEMM1)
    __shared__ _Float16 h2w[128][LDH];    // 33.0 KB (linear; walk is 2-way = free)
    __shared__ int dstL[128];

    const int lane = threadIdx.x & 63;
    const int w    = threadIdx.x >> 6;   // 0..7
    const int c16  = lane & 15;
    const int g    = lane >> 4;
    const int row0 = w * 16;

    // ---- stage weights (f16, transposed, zero-padded, swizzled) ----
    for (int i = threadIdx.x; i < 48 * 64; i += 512) {
        int n = i >> 6, k = i & 63;
        W1t[n][swz(n, k)] = (n < 47 && k < 47) ? (_Float16)W1[k * 47 + n] : (_Float16)0.f;
    }
    for (int i = threadIdx.x; i < 128 * 64; i += 512) {
        int n = i >> 6, k = i & 63;
        W2t[n][swz(n, k)] = (k < 47) ? (_Float16)W2[k * 128 + n] : (_Float16)0.f;
    }
    for (int i = threadIdx.x; i < 128 * LDK; i += 512)
        (&msgA[0][0])[i] = (_Float16)0.f;

    // ---- per-lane LN params ----
    float b1v[3], g1v[3], be1v[3];
#pragma unroll
    for (int n = 0; n < 3; ++n) {
        int cc = n * 16 + c16;
        bool vld = cc < 47;
        b1v[n]  = vld ? b1[cc]  : 0.f;
        g1v[n]  = vld ? g1[cc]  : 0.f;
        be1v[n] = vld ? be1[cc] : 0.f;
    }
    float b2v[8], g2v[8], be2v[8];
#pragma unroll
    for (int n = 0; n < 8; ++n) {
        int cc = n * 16 + c16;
        b2v[n] = b2[cc]; g2v[n] = g2[cc]; be2v[n] = be2[cc];
    }
    __syncthreads();

    // gather lane roles
    const int xr = lane >> 2;            // x: row within wave's 16 edges
    const int xc = (lane & 3) * 8;       //    8 channels per lane
    const int eg = lane / 11, ec = lane - eg * 11;   // ea: lanes<44
    const bool ea_act  = lane < 44;
    const bool geo_act = lane < 48;

    const int tbeg = blockIdx.x * tilesPerBlock;
    int tend = tbeg + tilesPerBlock;
    if (tend > ntiles) tend = ntiles;

    for (int tile = tbeg; tile < tend; ++tile) {
        const int base = tile * 128 + row0;   // this wave's 16 CSR positions

        // ---- Phase 1: gather (all loads issued as one batch) + commit ----
        {
            // x row: 4 lanes x 32B cover one 128B row
            int p = base + xr;
            bool vx = p < E;
            int s = vx ? se[p].x : 0;
            const float4* xp = (const float4*)(x + (size_t)s * 32 + xc);
            float4 xa = xp[0];
            float4 xb = xp[1];

            float eav0 = 0.f, eav1 = 0.f, eav2 = 0.f, eav3 = 0.f;
            if (ea_act) {
                int p0 = base + 0 * 4 + eg, p1 = base + 1 * 4 + eg;
                int p2 = base + 2 * 4 + eg, p3 = base + 3 * 4 + eg;
                int e0 = (p0 < E) ? se[p0].y : 0;
                int e1 = (p1 < E) ? se[p1].y : 0;
                int e2 = (p2 < E) ? se[p2].y : 0;
                int e3 = (p3 < E) ? se[p3].y : 0;
                eav0 = (p0 < E) ? ea[(size_t)e0 * 11 + ec] : 0.f;
                eav1 = (p1 < E) ? ea[(size_t)e1 * 11 + ec] : 0.f;
                eav2 = (p2 < E) ? ea[(size_t)e2 * 11 + ec] : 0.f;
                eav3 = (p3 < E) ? ea[(size_t)e3 * 11 + ec] : 0.f;
            }

            float gpix = 0.f, gpiy = 0.f, gpiz = 0.f;
            float gpjx = 0.f, gpjy = 0.f, gpjz = 0.f;
            float gnix = 0.f, gniy = 0.f, gniz = 0.f;
            float gnjx = 0.f, gnjy = 0.f, gnjz = 0.f;
            int pd = -1;
            if (geo_act) {
                int pg = base + c16;
                bool v = pg < E;
                int s2 = v ? se[pg].x : 0;
                int d2 = v ? dst_g[pg] : 0;
                pd = v ? d2 : -1;
                gpix = pos[d2 * 3 + 0]; gpiy = pos[d2 * 3 + 1]; gpiz = pos[d2 * 3 + 2];
                gpjx = pos[s2 * 3 + 0]; gpjy = pos[s2 * 3 + 1]; gpjz = pos[s2 * 3 + 2];
                gnix = nrm[d2 * 3 + 0]; gniy = nrm[d2 * 3 + 1]; gniz = nrm[d2 * 3 + 2];
                gnjx = nrm[s2 * 3 + 0]; gnjy = nrm[s2 * 3 + 1]; gnjz = nrm[s2 * 3 + 2];
            }

            // commit x
            {
                int r = row0 + xr;
                f16x8 hv;
                hv[0] = (_Float16)(vx ? xa.x : 0.f); hv[1] = (_Float16)(vx ? xa.y : 0.f);
                hv[2] = (_Float16)(vx ? xa.z : 0.f); hv[3] = (_Float16)(vx ? xa.w : 0.f);
                hv[4] = (_Float16)(vx ? xb.x : 0.f); hv[5] = (_Float16)(vx ? xb.y : 0.f);
                hv[6] = (_Float16)(vx ? xb.z : 0.f); hv[7] = (_Float16)(vx ? xb.w : 0.f);
                *(f16x8*)&msgA[r][swz(r, xc)] = hv;
            }
            // commit ea
            if (ea_act) {
                int r0 = row0 + 0 * 4 + eg; msgA[r0][swz(r0, 36 + ec)] = (_Float16)eav0;
                int r1 = row0 + 1 * 4 + eg; msgA[r1][swz(r1, 36 + ec)] = (_Float16)eav1;
                int r2 = row0 + 2 * 4 + eg; msgA[r2][swz(r2, 36 + ec)] = (_Float16)eav2;
                int r3 = row0 + 3 * 4 + eg; msgA[r3][swz(r3, 36 + ec)] = (_Float16)eav3;
            }
            // commit geometry (angle g per lane group)
            if (geo_act) {
                int r = row0 + c16;
                float px = gpjx - gpix, py = gpjy - gpiy, pz = gpjz - gpiz;
                float v1x, v1y, v1z, v2x, v2y, v2z;
                if (g == 0)      { v1x = gnix; v1y = gniy; v1z = gniz; v2x = px;   v2y = py;   v2z = pz; }
                else if (g == 1) { v1x = gnjx; v1y = gnjy; v1z = gnjz; v2x = px;   v2y = py;   v2z = pz; }
                else             { v1x = gnix; v1y = gniy; v1z = gniz; v2x = gnjx; v2y = gnjy; v2z = gnjz; }
                float cx = v1y * v2z - v1z * v2y;
                float cy = v1z * v2x - v1x * v2z;
                float cz = v1x * v2y - v1y * v2x;
                float ang = atan2f(sqrtf(cx * cx + cy * cy + cz * cz),
                                   v1x * v2x + v1y * v2y + v1z * v2z);
                msgA[r][swz(r, 33 + g)] = (_Float16)ang;
                if (g == 0) {
                    msgA[r][swz(r, 32)] = (_Float16)sqrtf(px * px + py * py + pz * pz);
                    dstL[r] = pd;
                }
            }
        }
        // no barrier: all LDS rows above are wave-private

        // ---- Phase 2: GEMM1 (16x48) + LN1 -> h1 back into msgA ----
        f32x4 acc1[3];
#pragma unroll
        for (int n = 0; n < 3; ++n) acc1[n] = (f32x4){0.f, 0.f, 0.f, 0.f};
#pragma unroll
        for (int ks = 0; ks < 2; ++ks) {
            int ar = row0 + c16;
            f16x8 a = *(const f16x8*)&msgA[ar][swz(ar, ks * 32 + g * 8)];
#pragma unroll
            for (int n = 0; n < 3; ++n) {
                int br = n * 16 + c16;
                f16x8 b = *(const f16x8*)&W1t[br][swz(br, ks * 32 + g * 8)];
                acc1[n] = __builtin_amdgcn_mfma_f32_16x16x32_f16(a, b, acc1[n], 0, 0, 0);
            }
        }
#pragma unroll
        for (int q = 0; q < 4; ++q) {
            float t0 = fmaxf(acc1[0][q] + b1v[0], 0.f);
            float t1 = fmaxf(acc1[1][q] + b1v[1], 0.f);
            float t2 = fmaxf(acc1[2][q] + b1v[2], 0.f);   // col 47 -> 0
            float s = t0 + t1 + t2;
            float s2 = t0 * t0 + t1 * t1 + t2 * t2;
#pragma unroll
            for (int m = 1; m < 16; m <<= 1) {
                s  += __shfl_xor(s,  m, 64);
                s2 += __shfl_xor(s2, m, 64);
            }
            float mu  = s * (1.f / 47.f);
            float var = s2 * (1.f / 47.f) - mu * mu;
            float rs  = rsqrtf(var + 1e-5f);
            int r = row0 + 4 * g + q;
            msgA[r][swz(r, c16)]      = (_Float16)((t0 - mu) * rs * g1v[0] + be1v[0]);
            msgA[r][swz(r, 16 + c16)] = (_Float16)((t1 - mu) * rs * g1v[1] + be1v[1]);
            msgA[r][swz(r, 32 + c16)] = (_Float16)((t2 - mu) * rs * g1v[2] + be1v[2]);
        }

        // ---- Phase 3: GEMM2 (16x128) + LN2 -> h2w ----
        f32x4 acc2[8];
#pragma unroll
        for (int n = 0; n < 8; ++n) acc2[n] = (f32x4){0.f, 0.f, 0.f, 0.f};
#pragma unroll
        for (int ks = 0; ks < 2; ++ks) {
            int ar = row0 + c16;
            f16x8 a = *(const f16x8*)&msgA[ar][swz(ar, ks * 32 + g * 8)];
#pragma unroll
            for (int n = 0; n < 8; ++n) {
                int br = n * 16 + c16;
                f16x8 b = *(const f16x8*)&W2t[br][swz(br, ks * 32 + g * 8)];
                acc2[n] = __builtin_amdgcn_mfma_f32_16x16x32_f16(a, b, acc2[n], 0, 0, 0);
            }
        }
#pragma unroll
        for (int q = 0; q < 4; ++q) {
            float t[8];
            float s = 0.f, s2 = 0.f;
#pragma unroll
            for (int n = 0; n < 8; ++n) {
                t[n] = fmaxf(acc2[n][q] + b2v[n], 0.f);
                s += t[n]; s2 += t[n] * t[n];
            }
#pragma unroll
            for (int m = 1; m < 16; m <<= 1) {
                s  += __shfl_xor(s,  m, 64);
                s2 += __shfl_xor(s2, m, 64);
            }
            float mu  = s * (1.f / 128.f);
            float var = s2 * (1.f / 128.f) - mu * mu;
            float rs  = rsqrtf(var + 1e-5f);
            int r = row0 + 4 * g + q;
#pragma unroll
            for (int n = 0; n < 8; ++n) {
                float o = (t[n] - mu) * rs * g2v[n] + be2v[n];
                h2w[r][n * 16 + c16] = (_Float16)o;
            }
        }

        // ---- Phase 4: segmented max walk (wave-private, dst-sorted rows) ----
        {
            float m0 = -INFINITY, m1 = -INFINITY;
            int segStart = 0;
            int dcur = dstL[row0];
#pragma unroll
            for (int r = 0; r < 16; ++r) {
                f16x2 pk = *(const f16x2*)&h2w[row0 + r][lane * 2];
                m0 = fmaxf(m0, (float)pk[0]);
                m1 = fmaxf(m1, (float)pk[1]);
                int dnext = (r < 15) ? dstL[row0 + r + 1] : -2;
                if (dnext != dcur) {
                    if (dcur >= 0) {
                        unsigned e0 = fenc(m0), e1 = fenc(m1);
                        unsigned* orow = out + (size_t)dcur * 128 + lane * 2;
                        if (segStart > 0 && r < 15) {
                            unsigned long long pk2 =
                                ((unsigned long long)e1 << 32) | (unsigned long long)e0;
                            *(unsigned long long*)orow = pk2;
                        } else {
                            atomicMax(orow,     e0);
                            atomicMax(orow + 1, e1);
                        }
                    }
                    m0 = -INFINITY; m1 = -INFINITY;
                    segStart = r + 1; dcur = dnext;
                }
            }
        }
    }
}

// ---------------- fallback: direct atomics, no CSR (round-2 form) ----------------
#define LDKF 72
__global__ __launch_bounds__(256) void edge_kernel_atomic(
    const float* __restrict__ x,   const float* __restrict__ pos,
    const float* __restrict__ nrm, const float* __restrict__ ea,
    const float* __restrict__ W1,  const float* __restrict__ b1,
    const float* __restrict__ g1,  const float* __restrict__ be1,
    const float* __restrict__ W2,  const float* __restrict__ b2,
    const float* __restrict__ g2,  const float* __restrict__ be2,
    const int* __restrict__ srcI,  const int* __restrict__ dstI,
    unsigned* __restrict__ out, int E, int ntiles)
{
    __shared__ _Float16 W1t[48][LDKF];
    __shared__ _Float16 W2t[128][LDKF];
    __shared__ _Float16 msgA[64][LDKF];
    __shared__ int dst_s[64];

    const int lane = threadIdx.x & 63;
    const int w    = threadIdx.x >> 6;
    const int c16  = lane & 15;
    const int g    = lane >> 4;

    for (int i = threadIdx.x; i < 48 * 64; i += 256) {
        int n = i >> 6, k = i & 63;
        W1t[n][k] = (n < 47 && k < 47) ? (_Float16)W1[k * 47 + n] : (_Float16)0.f;
    }
    for (int i = threadIdx.x; i < 128 * 64; i += 256) {
        int n = i >> 6, k = i & 63;
        W2t[n][k] = (k < 47) ? (_Float16)W2[k * 128 + n] : (_Float16)0.f;
    }
    for (int i = threadIdx.x; i < 64 * LDKF; i += 256)
        (&msgA[0][0])[i] = (_Float16)0.f;

    float b1v[3], g1v[3], be1v[3];
#pragma unroll
    for (int n = 0; n < 3; ++n) {
        int cc = n * 16 + c16;
        bool vld = cc < 47;
        b1v[n]  = vld ? b1[cc]  : 0.f;
        g1v[n]  = vld ? g1[cc]  : 0.f;
        be1v[n] = vld ? be1[cc] : 0.f;
    }
    float b2v[8], g2v[8], be2v[8];
#pragma unroll
    for (int n = 0; n < 8; ++n) {
        int cc = n * 16 + c16;
        b2v[n] = b2[cc]; g2v[n] = g2[cc]; be2v[n] = be2[cc];
    }
    __syncthreads();

    for (int tile = blockIdx.x; tile < ntiles; tile += gridDim.x) {
        const int base = tile * 64 + w * 16;
        const int row0 = w * 16;
#pragma unroll
        for (int i = 0; i < 8; ++i) {
            int el = i * 2 + (lane >> 5);
            int e  = base + el;
            int c  = lane & 31;
            float v = 0.f;
            if (e < E) v = x[(size_t)srcI[e] * 32 + c];
            msgA[row0 + el][c] = (_Float16)v;
        }
        if (lane < 44) {
            int eg = lane / 11, c = lane - eg * 11;
#pragma unroll
            for (int i = 0; i < 4; ++i) {
                int el = i * 4 + eg;
                int e  = base + el;
                float v = 0.f;
                if (e < E) v = ea[(size_t)e * 11 + c];
                msgA[row0 + el][36 + c] = (_Float16)v;
            }
        }
        if (lane < 48) {
            int el = c16;
            int e  = base + el;
            int s = 0, d = 0;
            bool vld = e < E;
            if (vld) { s = srcI[e]; d = dstI[e]; }
            float pix = pos[d * 3 + 0], piy = pos[d * 3 + 1], piz = pos[d * 3 + 2];
            float pjx = pos[s * 3 + 0], pjy = pos[s * 3 + 1], pjz = pos[s * 3 + 2];
            float nix = nrm[d * 3 + 0], niy = nrm[d * 3 + 1], niz = nrm[d * 3 + 2];
            float njx = nrm[s * 3 + 0], njy = nrm[s * 3 + 1], njz = nrm[s * 3 + 2];
            float px = pjx - pix, py = pjy - piy, pz = pjz - piz;
            float v1x, v1y, v1z, v2x, v2y, v2z;
            if (g == 0)      { v1x = nix; v1y = niy; v1z = niz; v2x = px;  v2y = py;  v2z = pz;  }
            else if (g == 1) { v1x = njx; v1y = njy; v1z = njz; v2x = px;  v2y = py;  v2z = pz;  }
        else             { v1x = nix; v1y = niy; v1z = niz; v2x = njx; v2y = njy; v2z = njz; }
            float cx = v1y * v2z - v1z * v2y;
            float cy = v1z * v2x - v1x * v2z;
            float cz = v1x * v2y - v1y * v2x;
            float ang = atan2f(sqrtf(cx * cx + cy * cy + cz * cz),
                               v1x * v2x + v1y * v2y + v1z * v2z);
            msgA[row0 + el][33 + g] = (_Float16)ang;
            if (g == 0) {
                msgA[row0 + el][32] = (_Float16)sqrtf(px * px + py * py + pz * pz);
                dst_s[row0 + el] = vld ? d : -1;
            }
        }

        f32x4 acc1[3];
#pragma unroll
        for (int n = 0; n < 3; ++n) acc1[n] = (f32x4){0.f, 0.f, 0.f, 0.f};
#pragma unroll
        for (int ks = 0; ks < 2; ++ks) {
            f16x8 a = *(const f16x8*)&msgA[row0 + c16][ks * 32 + g * 8];
#pragma unroll
            for (int n = 0; n < 3; ++n) {
                f16x8 b = *(const f16x8*)&W1t[n * 16 + c16][ks * 32 + g * 8];
                acc1[n] = __builtin_amdgcn_mfma_f32_16x16x32_f16(a, b, acc1[n], 0, 0, 0);
            }
        }
#pragma unroll
        for (int q = 0; q < 4; ++q) {
            float t0 = fmaxf(acc1[0][q] + b1v[0], 0.f);
            float t1 = fmaxf(acc1[1][q] + b1v[1], 0.f);
            float t2 = fmaxf(acc1[2][q] + b1v[2], 0.f);
            float s = t0 + t1 + t2;
            float s2 = t0 * t0 + t1 * t1 + t2 * t2;
#pragma unroll
            for (int m = 1; m < 16; m <<= 1) {
                s  += __shfl_xor(s,  m, 64);
                s2 += __shfl_xor(s2, m, 64);
            }
            float mu  = s * (1.f / 47.f);
            float var = s2 * (1.f / 47.f) - mu * mu;
            float rs  = rsqrtf(var + 1e-5f);
            int r = row0 + 4 * g + q;
            msgA[r][c16]      = (_Float16)((t0 - mu) * rs * g1v[0] + be1v[0]);
            msgA[r][16 + c16] = (_Float16)((t1 - mu) * rs * g1v[1] + be1v[1]);
            msgA[r][32 + c16] = (_Float16)((t2 - mu) * rs * g1v[2] + be1v[2]);
        }

        f32x4 acc2[8];
#pragma unroll
        for (int n = 0; n < 8; ++n) acc2[n] = (f32x4){0.f, 0.f, 0.f, 0.f};
#pragma unroll
        for (int ks = 0; ks < 2; ++ks) {
            f16x8 a = *(const f16x8*)&msgA[row0 + c16][ks * 32 + g * 8];
#pragma unroll
            for (int n = 0; n < 8; ++n) {
                f16x8 b = *(const f16x8*)&W2t[n * 16 + c16][ks * 32 + g * 8];
                acc2[n] = __builtin_amdgcn_mfma_f32_16x16x32_f16(a, b, acc2[n], 0, 0, 0);
            }
        }
        int4 dd = *(const int4*)&dst_s[row0 + 4 * g];
#pragma unroll
        for (int q = 0; q < 4; ++q) {
            float t[8];
            float s = 0.f, s2 = 0.f;
#pragma unroll
            for (int n = 0; n < 8; ++n) {
                t[n] = fmaxf(acc2[n][q] + b2v[n], 0.f);
                s += t[n]; s2 += t[n] * t[n];
            }
#pragma unroll
            for (int m = 1; m < 16; m <<= 1) {
                s  += __shfl_xor(s,  m, 64);
                s2 += __shfl_xor(s2, m, 64);
            }
            float mu  = s * (1.f / 128.f);
            float var = s2 * (1.f / 128.f) - mu * mu;
            float rs  = rsqrtf(var + 1e-5f);
            int d = (&dd.x)[q];
            if (d >= 0) {
                unsigned* orow = out + (size_t)d * 128u;
#pragma unroll
                for (int n = 0; n < 8; ++n) {
                    float o = (t[n] - mu) * rs * g2v[n] + be2v[n];
                    atomicMax(orow + n * 16 + c16, fenc(o));
                }
            }
        }
    }
}

extern "C" void kernel_launch(void* const* d_in, const int* in_sizes, int n_in,
                              void* d_out, int out_size, void* d_ws, size_t ws_size,
                              hipStream_t stream) {
    const float* x   = (const float*)d_in[0];
    const float* pos = (const float*)d_in[1];
    const float* nrm = (const float*)d_in[2];
    const float* ea  = (const float*)d_in[3];
    const float* W1  = (const float*)d_in[4];
    const float* b1  = (const float*)d_in[5];
    const float* g1  = (const float*)d_in[6];
    const float* be1 = (const float*)d_in[7];
    const float* W2  = (const float*)d_in[8];
    const float* b2  = (const float*)d_in[9];
    const float* g2  = (const float*)d_in[10];
    const float* be2 = (const float*)d_in[11];
    const int*   idx = (const int*)d_in[12];

    const int N = in_sizes[0] / 32;
    const int E = in_sizes[3] / 11;
    const int* srcI = idx;
    const int* dstI = idx + E;

    unsigned* outU = (unsigned*)d_out;
    const int n = N * 128;

    init_out_kernel<<<(n / 4 + 255) / 256, 256, 0, stream>>>(outU, n / 4);

    const int nb = (N + 1023) / 1024;
    // ws layout: se[E] int2 | counts[N] | nextp[N] | dst_g[E] | bsums[nb]
    const size_t needed = (size_t)E * 8 + (size_t)(2LL * N + E + nb) * 4;

    if (ws_size >= needed) {
        int2* se     = (int2*)d_ws;
        int*  counts = (int*)(se + E);
        int*  nextp  = counts + N;
        int*  dst_g  = nextp + N;
        int*  bsums  = dst_g + E;

        zero_kernel<<<(N + 255) / 256, 256, 0, stream>>>(counts, N);
        hist_kernel<<<(E + 255) / 256, 256, 0, stream>>>(dstI, counts, E);
        scan_blk<<<nb, 1024, 0, stream>>>(counts, nextp, bsums, N);
        scan_blk<<<1, 1024, 0, stream>>>(bsums, bsums, (int*)nullptr, nb);
        scan_add<<<nb, 1024, 0, stream>>>(nextp, bsums, N);
        scatter_kernel<<<(E + 255) / 256, 256, 0, stream>>>(srcI, dstI, nextp,
                                                            se, dst_g, E);

        const int ntiles = (E + 127) / 128;
        int grid = ntiles < 512 ? ntiles : 512;    // 2 blocks/CU resident, persistent
        int tpb  = (ntiles + grid - 1) / grid;
        edge_kernel_csr<<<grid, 512, 0, stream>>>(x, pos, nrm, ea,
                                                  W1, b1, g1, be1,
                                                  W2, b2, g2, be2,
                                                  se, dst_g,
                                                  outU, E, ntiles, tpb);
    } else {
        const int ntiles = (E + 63) / 64;
        int grid = ntiles < 4096 ? ntiles : 4096;
        edge_kernel_atomic<<<grid, 256, 0, stream>>>(x, pos, nrm, ea,
                                                     W1, b1, g1, be1,
                                                     W2, b2, g2, be2,
                                                     srcI, dstI, outU, E, ntiles);
    }

    finalize_out_kernel<<<(n + 255) / 256, 256, 0, stream>>>((float*)d_out, n);
}